// Round 1
// baseline (414.887 us; speedup 1.0000x reference)
//
#include <hip/hip_runtime.h>
#include <cmath>

#define NN 512

__device__ __forceinline__ int is_inf_f(float x) {
    return (__float_as_uint(x) & 0x7fffffffu) == 0x7f800000u;
}

// e = ef[1:4] = sqrt(3) * u[[1,2,0]] with the reference's exact epsilon fudges
__device__ __forceinline__ void edge_vec(float ci0, float ci1, float ci2,
                                         float cj0, float cj1, float cj2,
                                         float& e0, float& e1, float& e2) {
    float d0 = ci0 - cj0, d1 = ci1 - cj1, d2 = ci2 - cj2;
    float den = sqrtf(d0*d0 + d1*d1 + d2*d2 + 1e-12f) + 1e-5f;
    float r = 1.0f / den;
    d0 *= r; d1 *= r; d2 *= r;
    float n = sqrtf(d0*d0 + d1*d1 + d2*d2 + 1e-12f);
    float s = 1.7320508075688772f / n;
    e0 = d1 * s;  // sqrt3*u_y
    e1 = d2 * s;  // sqrt3*u_z
    e2 = d0 * s;  // sqrt3*u_x
}

// K1: block = (b, i-quad). Transpose attn_disp -> ad (inf->0, required output,
// i-major) AND adT (j-major, scribbled into the mask_out region — dead until
// k_final rewrites it). Also edge features + normalizer.
// LDS tile: rows = (il*64 + jl), 16 payload words padded to 20.
// Pad-20: row*20 mod 32 cycles 0,20,8,28,16,4,24,12 over 8 consecutive rows →
// consecutive-row ds_write_b128 hits all 8 bank-quads (conflict-free / full BW).
__global__ __launch_bounds__(256) void k_trans(
    const float* __restrict__ disp, const float* __restrict__ coords,
    float* __restrict__ ad_out, float* __restrict__ adT_out,
    float* __restrict__ ef_out, float* __restrict__ ws_norm)
{
    __shared__ float L[256 * 20];          // 20 KiB
    const int blk = blockIdx.x;            // 512 = 4 b * 128 i-quads
    const int b   = blk >> 7;
    const int i0  = (blk & 127) << 2;
    const int tid = threadIdx.x;
    const int il  = tid >> 6;              // wave id == local i (0..3)
    const int jl  = tid & 63;
    const int i   = i0 + il;
    const float ci0 = coords[(b*NN+i)*3+0];
    const float ci1 = coords[(b*NN+i)*3+1];
    const float ci2 = coords[(b*NN+i)*3+2];
    int cnt = 0;
    for (int ch = 0; ch < 8; ch++) {       // j-chunks of 64
        const int j = ch*64 + jl;
        float v[16];
        #pragma unroll
        for (int h = 0; h < 16; h++) {
            float x = disp[(size_t)((b*16+h)*NN + i)*NN + j];   // 256B coalesced
            int bad = is_inf_f(x);
            if (h == 0) cnt += 1 - bad;
            v[h] = bad ? 0.0f : x;
        }
        // ad (i-major): lane owns its full 64B line (proven pattern)
        float4* dst = (float4*)(ad_out + (size_t)((b*NN+i)*NN + j)*16);
        dst[0] = make_float4(v[0], v[1], v[2], v[3]);
        dst[1] = make_float4(v[4], v[5], v[6], v[7]);
        dst[2] = make_float4(v[8], v[9], v[10], v[11]);
        dst[3] = make_float4(v[12], v[13], v[14], v[15]);
        // edge features
        {
            const float cj0 = coords[(b*NN+j)*3+0];
            const float cj1 = coords[(b*NN+j)*3+1];
            const float cj2 = coords[(b*NN+j)*3+2];
            float e0, e1, e2;
            edge_vec(ci0, ci1, ci2, cj0, cj1, cj2, e0, e1, e2);
            ((float4*)ef_out)[(size_t)(b*NN+i)*NN + j] = make_float4(1.0f, e0, e1, e2);
        }
        // stage tile for the transpose: row == tid
        {
            float4* Lr = (float4*)(L + tid*20);
            Lr[0] = make_float4(v[0], v[1], v[2], v[3]);
            Lr[1] = make_float4(v[4], v[5], v[6], v[7]);
            Lr[2] = make_float4(v[8], v[9], v[10], v[11]);
            Lr[3] = make_float4(v[12], v[13], v[14], v[15]);
        }
        __syncthreads();
        // adT (j-major): per j, 4i x 16h = 256B contiguous
        #pragma unroll
        for (int p = 0; p < 4; p++) {
            const int jj  = (tid >> 4) + p*16;   // 0..63
            const int f   = tid & 15;
            const int iw  = f >> 2, w4 = f & 3;
            const int row = iw*64 + jj;
            float4 val = *(const float4*)(L + row*20 + w4*4);
            ((float4*)adT_out)[(size_t)((b*NN + ch*64 + jj)*NN + (i0 + iw))*4 + w4] = val;
        }
        __syncthreads();
    }
    // normalizer[b,i] = sqrt(#non-inf in attn_disp[b,0,i,:]) — full row covered
    #pragma unroll
    for (int off = 32; off >= 1; off >>= 1) cnt += __shfl_xor(cnt, off);
    if (jl == 0) ws_norm[b*NN + i] = sqrtf((float)cnt);
}

// K2: block = (b,j). Wave wv owns 16 of the 64 hidden cols (cols 0..31 = net A,
// 32..63 = net B). Fully coalesced adT reads (lane = i), weights via uniform
// loads (readfirstlane-forced scalar address), NO LDS, shuffle-butterfly reduce.
__global__ __launch_bounds__(256) void k_reduce2(
    const float* __restrict__ adT, const float* __restrict__ coords,
    const float* __restrict__ wA, const float* __restrict__ wB,  // fc1_w1, fc2_w1 (16x32)
    float* __restrict__ ws)
{
    const int blk  = blockIdx.x;           // 2048 = B*N
    const int b    = blk >> 9, j = blk & 511;
    const int tid  = threadIdx.x;
    const int lane = tid & 63;
    const int wv   = tid >> 6;             // 0..3
    const float cj0 = coords[(b*NN+j)*3+0];
    const float cj1 = coords[(b*NN+j)*3+1];
    const float cj2 = coords[(b*NN+j)*3+2];
    // precompute e for this lane's 8 edges (i = k*64 + lane); also Se partials
    float e0[8], e1[8], e2[8];
    float se0 = 0.f, se1 = 0.f, se2 = 0.f;
    #pragma unroll
    for (int k = 0; k < 8; k++) {
        const int i = k*64 + lane;
        const float ci0 = coords[(b*NN+i)*3+0];
        const float ci1 = coords[(b*NN+i)*3+1];
        const float ci2 = coords[(b*NN+i)*3+2];
        edge_vec(ci0, ci1, ci2, cj0, cj1, cj2, e0[k], e1[k], e2[k]);
        se0 += e0[k]; se1 += e1[k]; se2 += e2[k];
    }
    const float* __restrict__ W = (wv & 2) ? wB : wA;
    const int cbase = (wv & 1) * 16;
    const size_t abase = (size_t)((b*NN + j) * NN) * 16;
    float* accg = ws + 2048*4 + (size_t)blk*256;   // [net][w][c] rows of 32
    for (int cb = 0; cb < 4; cb++) {
        // 4 cols per block-step; weights through a scalar (uniform) address
        float wt[4][16];
        #pragma unroll
        for (int cc = 0; cc < 4; cc++) {
            const int col = __builtin_amdgcn_readfirstlane(cbase + cb*4 + cc);
            #pragma unroll
            for (int h = 0; h < 16; h++) wt[cc][h] = W[h*32 + col];
        }
        float acc[4][4];
        #pragma unroll
        for (int cc = 0; cc < 4; cc++)
            #pragma unroll
            for (int w = 0; w < 4; w++) acc[cc][w] = 0.f;
        // hand-pipelined i-loop: coalesced 64B/lane loads of adT row (b,j)
        float4 A0, A1, A2, A3;
        {
            const float4* s = (const float4*)(adT + abase + (size_t)lane*16);
            A0 = s[0]; A1 = s[1]; A2 = s[2]; A3 = s[3];
        }
        #pragma unroll
        for (int k = 0; k < 8; k++) {
            float4 N0, N1, N2, N3;
            if (k < 7) {
                const float4* s = (const float4*)(adT + abase + (size_t)((k+1)*64 + lane)*16);
                N0 = s[0]; N1 = s[1]; N2 = s[2]; N3 = s[3];
            }
            #pragma unroll
            for (int cc = 0; cc < 4; cc++) {
                float t;
                t = A0.x * wt[cc][0];
                t = fmaf(A0.y, wt[cc][1],  t);
                t = fmaf(A0.z, wt[cc][2],  t);
                t = fmaf(A0.w, wt[cc][3],  t);
                t = fmaf(A1.x, wt[cc][4],  t);
                t = fmaf(A1.y, wt[cc][5],  t);
                t = fmaf(A1.z, wt[cc][6],  t);
                t = fmaf(A1.w, wt[cc][7],  t);
                t = fmaf(A2.x, wt[cc][8],  t);
                t = fmaf(A2.y, wt[cc][9],  t);
                t = fmaf(A2.z, wt[cc][10], t);
                t = fmaf(A2.w, wt[cc][11], t);
                t = fmaf(A3.x, wt[cc][12], t);
                t = fmaf(A3.y, wt[cc][13], t);
                t = fmaf(A3.z, wt[cc][14], t);
                t = fmaf(A3.w, wt[cc][15], t);
                const float hq = fmaxf(t * 0.25f, 0.f) * 1.4142135623730951f;
                acc[cc][0] += hq;
                acc[cc][1] = fmaf(e0[k], hq, acc[cc][1]);
                acc[cc][2] = fmaf(e1[k], hq, acc[cc][2]);
                acc[cc][3] = fmaf(e2[k], hq, acc[cc][3]);
            }
            A0 = N0; A1 = N1; A2 = N2; A3 = N3;
        }
        // butterfly over all 64 lanes; lane q stores its col/w
        #pragma unroll
        for (int cc = 0; cc < 4; cc++)
            #pragma unroll
            for (int w = 0; w < 4; w++) {
                float vs = acc[cc][w];
                vs += __shfl_xor(vs, 1);  vs += __shfl_xor(vs, 2);
                vs += __shfl_xor(vs, 4);  vs += __shfl_xor(vs, 8);
                vs += __shfl_xor(vs, 16); vs += __shfl_xor(vs, 32);
                const int q = cc*4 + w;
                if (lane == q) {
                    const int C = wv*16 + cb*4 + cc;         // global col 0..63
                    accg[((C >> 5)*4 + w)*32 + (C & 31)] = vs;
                }
            }
    }
    // Se = sum_i e : wave 0 has all 512 i across its 8 rounds
    if (wv == 0) {
        #pragma unroll
        for (int off = 1; off < 64; off <<= 1) {
            se0 += __shfl_xor(se0, off);
            se1 += __shfl_xor(se1, off);
            se2 += __shfl_xor(se2, off);
        }
        if (lane == 0) {
            float* seg = ws + 2048 + blk*3;
            seg[0] = se0; seg[1] = se1; seg[2] = se2;
        }
    }
}

// K3: blocks 0..7 = per-node W2 + Wigner/gate algebra (unchanged, verified);
// blocks 8..519 = mask passthrough (adT region is dead now) + coords copy.
__global__ __launch_bounds__(256) void k_final(
    const float* __restrict__ ws,
    const float* __restrict__ w2a,   // fc1_w2 (32x14)
    const float* __restrict__ w2b,   // fc2_w2 (32x12)
    float* __restrict__ nf_out,
    const float* __restrict__ mask, float* __restrict__ mask_out,
    const float* __restrict__ coords, float* __restrict__ coords_out)
{
    if (blockIdx.x >= 8) {
        const int cblk = blockIdx.x - 8;              // 0..511
        const float4* mi = (const float4*)mask;
        float4* mo = (float4*)mask_out;
        const size_t base = (size_t)cblk * 8192;
        #pragma unroll
        for (int r = 0; r < 32; r++) mo[base + r*256 + threadIdx.x] = mi[base + r*256 + threadIdx.x];
        if (cblk == 0) {
            for (int idx = threadIdx.x; idx < 4*NN*3; idx += 256) coords_out[idx] = coords[idx];
        }
        return;
    }
    const int bj = blockIdx.x*256 + threadIdx.x;   // 2048
    const float inv = 1.0f / ws[bj];
    const float s  = 512.0f * inv;                 // nf0 scalar = N/norm
    const float vv0 = ws[2048 + bj*3 + 0] * inv;
    const float vv1 = ws[2048 + bj*3 + 1] * inv;
    const float vv2 = ws[2048 + bj*3 + 2] * inv;
    const float* acc = ws + 2048*4 + (size_t)bj*256;
    const float ksc = 0.17677669529663687f;        // 1/sqrt(32) (fc second layer)
    // net1: S0 = plain sums @ W2, S1[k] = e_k-weighted sums @ W2
    float S0[14], S1[3][14];
    #pragma unroll
    for (int cc = 0; cc < 14; cc++) { S0[cc]=0.f; S1[0][cc]=0.f; S1[1][cc]=0.f; S1[2][cc]=0.f; }
    for (int c = 0; c < 32; c++) {
        const float p = acc[c], q0 = acc[32+c], q1 = acc[64+c], q2 = acc[96+c];
        #pragma unroll
        for (int cc = 0; cc < 14; cc++) {
            const float w = w2a[c*14+cc];
            S0[cc]    = fmaf(p,  w, S0[cc]);
            S1[0][cc] = fmaf(q0, w, S1[0][cc]);
            S1[1][cc] = fmaf(q1, w, S1[1][cc]);
            S1[2][cc] = fmaf(q2, w, S1[2][cc]);
        }
    }
    #pragma unroll
    for (int cc = 0; cc < 14; cc++) { S0[cc]*=ksc; S1[0][cc]*=ksc; S1[1][cc]*=ksc; S1[2][cc]*=ksc; }
    const float is2 = 0.7071067811865476f;   // 1/sqrt2
    const float is3 = 0.5773502691896258f;   // 1/sqrt3
    float x0[4];
    #pragma unroll
    for (int k = 0; k < 4; k++)
        x0[k] = inv*is2*( s*S0[k] + is3*(vv0*S1[0][4+k] + vv1*S1[1][4+k] + vv2*S1[2][4+k]) );
    const float vv[3] = {vv0, vv1, vv2};
    float x8[3];
    #pragma unroll
    for (int k = 0; k < 3; k++)
        x8[k] = inv*is2*( s*S1[k][8] + vv[k]*S0[10] );
    const float E12_0=S1[0][12], E12_1=S1[1][12], E12_2=S1[2][12];
    float x14[3];
    x14[0] = inv*is2*(vv1*E12_2 - vv2*E12_1);
    x14[1] = inv*is2*(vv2*E12_0 - vv0*E12_2);
    x14[2] = inv*is2*(vv0*E12_1 - vv1*E12_0);
    // gate
    const float a0 = fmaxf(x0[0],0.f), a1 = fmaxf(x0[1],0.f);
    const float g1 = fmaxf(x0[2],0.f), g3 = fmaxf(x0[3],0.f);
    const float p0=x8[0]*g1,  p1=x8[1]*g1,  p2=x8[2]*g1;
    const float q0_=x14[0]*g3, q1_=x14[1]*g3, q2_=x14[2]*g3;
    // net2
    float T0[12], T1[3][12];
    #pragma unroll
    for (int cc = 0; cc < 12; cc++){ T0[cc]=0.f; T1[0][cc]=0.f; T1[1][cc]=0.f; T1[2][cc]=0.f; }
    const float* acc2 = acc + 128;
    for (int c = 0; c < 32; c++) {
        const float p = acc2[c], r0 = acc2[32+c], r1 = acc2[64+c], r2 = acc2[96+c];
        #pragma unroll
        for (int cc = 0; cc < 12; cc++) {
            const float w = w2b[c*12+cc];
            T0[cc]    = fmaf(p,  w, T0[cc]);
            T1[0][cc] = fmaf(r0, w, T1[0][cc]);
            T1[1][cc] = fmaf(r1, w, T1[1][cc]);
            T1[2][cc] = fmaf(r2, w, T1[2][cc]);
        }
    }
    #pragma unroll
    for (int cc = 0; cc < 12; cc++){ T0[cc]*=ksc; T1[0][cc]*=ksc; T1[1][cc]*=ksc; T1[2][cc]*=ksc; }
    const float is6  = 0.4082482904638631f;    // 1/sqrt6
    const float is12 = 0.28867513459481287f;   // 1/sqrt12
    const float E0[3] = {T1[0][0], T1[1][0], T1[2][0]};
    const float E1[3] = {T1[0][1], T1[1][1], T1[2][1]};
    const float E4[3] = {T1[0][4], T1[1][4], T1[2][4]};
    const float E8[3] = {T1[0][8], T1[1][8], T1[2][8]};
    const float cq0 = q1_*E4[2] - q2_*E4[1];
    const float cq1 = q2_*E4[0] - q0_*E4[2];
    const float cq2 = q0_*E4[1] - q1_*E4[0];
    const float cp0 = p1*E8[2] - p2*E8[1];
    const float cp1 = p2*E8[0] - p0*E8[2];
    const float cp2 = p0*E8[1] - p1*E8[0];
    float o[6];
    o[0] = inv*( is6*(a0*E0[0] + a1*E1[0]) + is6*p0*T0[2] + is12*cq0 );
    o[1] = inv*( is6*(a0*E0[1] + a1*E1[1]) + is6*p1*T0[2] + is12*cq1 );
    o[2] = inv*( is6*(a0*E0[2] + a1*E1[2]) + is6*p2*T0[2] + is12*cq2 );
    o[3] = inv*( is12*cp0 + is6*q0_*T0[10] );
    o[4] = inv*( is12*cp1 + is6*q1_*T0[10] );
    o[5] = inv*( is12*cp2 + is6*q2_*T0[10] );
    #pragma unroll
    for (int k = 0; k < 6; k++) nf_out[bj*6+k] = o[k];
}

extern "C" void kernel_launch(void* const* d_in, const int* in_sizes, int n_in,
                              void* d_out, int out_size, void* d_ws, size_t ws_size,
                              hipStream_t stream) {
    const float* disp   = (const float*)d_in[0];   // (4,16,512,512)
    const float* mask   = (const float*)d_in[1];   // (64,512,512)
    const float* coords = (const float*)d_in[2];   // (4,512,3)
    const float* fc1w1  = (const float*)d_in[3];   // (16,32)
    const float* fc1w2  = (const float*)d_in[4];   // (32,14)
    const float* fc2w1  = (const float*)d_in[5];   // (16,32)
    const float* fc2w2  = (const float*)d_in[6];   // (32,12)
    float* out = (float*)d_out;
    float* ad_out     = out;                        // 16,777,216
    float* mask_out   = out + 16777216;             // 16,777,216
    float* coords_out = out + 33554432;             // 6,144
    float* nf_out     = coords_out + 6144;          // 12,288
    float* ef_out     = nf_out + 12288;             // 4,194,304
    float* ws = (float*)d_ws;   // norm[2048] | Se[2048*3] | acc[2048*256]  (~2.03 MiB)

    // adT (b,j,i,h) lives in the mask_out region until k_final overwrites it:
    // exactly 16,777,216 floats — same size as the mask. Dead after k_reduce2.
    float* adT = mask_out;

    k_trans  <<<512,  256, 0, stream>>>(disp, coords, ad_out, adT, ef_out, ws);
    k_reduce2<<<2048, 256, 0, stream>>>(adT, coords, fc1w1, fc2w1, ws);
    k_final  <<<520,  256, 0, stream>>>(ws, fc1w2, fc2w2, nf_out,
                                        mask, mask_out, coords, coords_out);
}